// Round 1
// 1055.699 us; speedup vs baseline: 1.1898x; 1.1898x over previous
//
#include <hip/hip_runtime.h>
#include <stdint.h>

typedef unsigned short u16;
typedef __attribute__((ext_vector_type(8))) __bf16 bf16x8;
typedef __attribute__((ext_vector_type(4))) float f32x4;

#define GLOBAL_AS __attribute__((address_space(1)))
#define LDS_AS __attribute__((address_space(3)))

__device__ __forceinline__ float bf2f(u16 v) {
  union { uint32_t u; float f; } x; x.u = (uint32_t)v << 16; return x.f;
}
__device__ __forceinline__ u16 f2bf(float f) {
  union { float f; uint32_t u; } x; x.f = f;
  uint32_t u = x.u + 0x7fffu + ((x.u >> 16) & 1u);
  return (u16)(u >> 16);
}

// ---------------------------------------------------------------------------
// Kernel 0: pack fp32 weights -> bf16, transposed.
// WT[2048][512]: rows [0,512)=Wq^T, [512,1024)=Wk^T, [1024,1536)=Wv^T,
//                rows [1536,2048)=Wo^T.  WT[n][k] = W(k,n) as bf16 (RNE).
// ---------------------------------------------------------------------------
__global__ void pack_weights(const float* __restrict__ Wq, const float* __restrict__ Wk,
                             const float* __restrict__ Wv, const float* __restrict__ Wo,
                             u16* __restrict__ WT) {
  int g = blockIdx.x * 256 + threadIdx.x;      // [0, 2048*512)
  int n = g >> 9;
  int k = g & 511;
  const float* src = (n < 1024) ? ((n < 512) ? Wq : Wk) : ((n < 1536) ? Wv : Wo);
  WT[g] = f2bf(src[k * 512 + (n & 511)]);
}

// ---------------------------------------------------------------------------
// Kernel 0b: hidden_states fp32 -> bf16 (RNE), streaming, 8 elems/thread.
// Output goes into scratch (d_out reused; not needed until final GEMM).
// ---------------------------------------------------------------------------
__global__ __launch_bounds__(256) void convert_bf16(const float* __restrict__ src,
                                                    u16* __restrict__ dst) {
  long i = ((long)blockIdx.x * 256 + threadIdx.x) * 8;
  float4 a = *(const float4*)(src + i);
  float4 b = *(const float4*)(src + i + 4);
  uint4 w;
  w.x = (uint32_t)f2bf(a.x) | ((uint32_t)f2bf(a.y) << 16);
  w.y = (uint32_t)f2bf(a.z) | ((uint32_t)f2bf(a.w) << 16);
  w.z = (uint32_t)f2bf(b.x) | ((uint32_t)f2bf(b.y) << 16);
  w.w = (uint32_t)f2bf(b.z) | ((uint32_t)f2bf(b.w) << 16);
  *(uint4*)(dst + i) = w;
}

// ---------------------------------------------------------------------------
// GEMM core: C[M,N] = A[M,K=512] * BT[N,K=512]^T (+ bias), fp32 accumulate.
// 128x128 tile, BK=32, 256 threads = 2x2 waves, each wave 4x4 MFMA 16x16x32.
// Grid: blockIdx.x = N-tile (fast-varying -> consecutive blocks share A-tile),
//       blockIdx.y = M-tile.
// AF32: A is fp32 in global, converted to bf16 during LDS staging (ds_write).
//  else A is bf16, staged via global_load_lds width-16.
// CF32: C stored fp32 (+fp32 bias); else C stored bf16.
// ---------------------------------------------------------------------------
template <bool AF32, bool CF32>
__global__ __launch_bounds__(256, 2) void gemm_core(
    const void* __restrict__ Ap, int lda,
    const u16* __restrict__ BT,          // [N][512] bf16 row-major (pre-transposed)
    const float* __restrict__ bias,      // nullable, [N] fp32
    void* __restrict__ Cp, int ldc)
{
  __shared__ __align__(16) u16 lsA[128 * 32];   // [row m][k] 8KB
  __shared__ __align__(16) u16 lsB[128 * 32];   // [row n][k] 8KB

  const int tid  = threadIdx.x;
  const int wave = tid >> 6;
  const int lane = tid & 63;
  const int quad = lane >> 4;
  const int lrow = lane & 15;
  const int wm = wave & 1;
  const int wn = wave >> 1;

  const long m0 = (long)blockIdx.y * 128;
  const int  n0 = blockIdx.x * 128;

  // staging slots: slot = s*256 + tid; row = slot>>2, k-chunk = (slot&3)*8
  const int s0 = tid, s1 = 256 + tid;
  const u16* bgp0 = BT + (long)(n0 + (s0 >> 2)) * 512 + (s0 & 3) * 8;
  const u16* bgp1 = BT + (long)(n0 + (s1 >> 2)) * 512 + (s1 & 3) * 8;
  u16* lB0 = lsB + wave * 512;                 // wave-uniform LDS bases
  u16* lB1 = lsB + 2048 + wave * 512;

  // A staging pointers (either dtype); slot->LDS offset is slot*8 u16.
  const float* agf0 = (const float*)Ap + (m0 + (s0 >> 2)) * (long)lda + (s0 & 3) * 8;
  const float* agf1 = (const float*)Ap + (m0 + (s1 >> 2)) * (long)lda + (s1 & 3) * 8;
  const u16*   agb0 = (const u16*)Ap + (m0 + (s0 >> 2)) * (long)lda + (s0 & 3) * 8;
  const u16*   agb1 = (const u16*)Ap + (m0 + (s1 >> 2)) * (long)lda + (s1 & 3) * 8;
  u16* lA0 = lsA + wave * 512;
  u16* lA1 = lsA + 2048 + wave * 512;

  f32x4 acc[4][4] = {};

  for (int k0 = 0; k0 < 512; k0 += 32) {
    __syncthreads();   // previous iteration's ds_reads complete before overwrite
    if constexpr (AF32) {
      // load 2x8 fp32, convert RNE -> bf16, ds_write_b128 per slot
      float4 x0 = *(const float4*)(agf0 + k0);
      float4 x1 = *(const float4*)(agf0 + k0 + 4);
      float4 y0 = *(const float4*)(agf1 + k0);
      float4 y1 = *(const float4*)(agf1 + k0 + 4);
      uint4 w0, w1;
      w0.x = (uint32_t)f2bf(x0.x) | ((uint32_t)f2bf(x0.y) << 16);
      w0.y = (uint32_t)f2bf(x0.z) | ((uint32_t)f2bf(x0.w) << 16);
      w0.z = (uint32_t)f2bf(x1.x) | ((uint32_t)f2bf(x1.y) << 16);
      w0.w = (uint32_t)f2bf(x1.z) | ((uint32_t)f2bf(x1.w) << 16);
      w1.x = (uint32_t)f2bf(y0.x) | ((uint32_t)f2bf(y0.y) << 16);
      w1.y = (uint32_t)f2bf(y0.z) | ((uint32_t)f2bf(y0.w) << 16);
      w1.z = (uint32_t)f2bf(y1.x) | ((uint32_t)f2bf(y1.y) << 16);
      w1.w = (uint32_t)f2bf(y1.z) | ((uint32_t)f2bf(y1.w) << 16);
      *(uint4*)(lsA + s0 * 8) = w0;
      *(uint4*)(lsA + s1 * 8) = w1;
    } else {
      __builtin_amdgcn_global_load_lds((GLOBAL_AS const uint32_t*)(agb0 + k0),
                                       (LDS_AS uint32_t*)lA0, 16, 0, 0);
      __builtin_amdgcn_global_load_lds((GLOBAL_AS const uint32_t*)(agb1 + k0),
                                       (LDS_AS uint32_t*)lA1, 16, 0, 0);
    }
    __builtin_amdgcn_global_load_lds((GLOBAL_AS const uint32_t*)(bgp0 + k0),
                                     (LDS_AS uint32_t*)lB0, 16, 0, 0);
    __builtin_amdgcn_global_load_lds((GLOBAL_AS const uint32_t*)(bgp1 + k0),
                                     (LDS_AS uint32_t*)lB1, 16, 0, 0);
    __syncthreads();   // drains vmcnt+lgkmcnt: staging visible

    bf16x8 af[4], bfr[4];
#pragma unroll
    for (int t = 0; t < 4; ++t) {
      af[t]  = *(const bf16x8*)(lsA + (wm * 64 + t * 16 + lrow) * 32 + quad * 8);
      bfr[t] = *(const bf16x8*)(lsB + (wn * 64 + t * 16 + lrow) * 32 + quad * 8);
    }
#pragma unroll
    for (int mt = 0; mt < 4; ++mt)
#pragma unroll
      for (int nt = 0; nt < 4; ++nt)
        acc[mt][nt] = __builtin_amdgcn_mfma_f32_16x16x32_bf16(af[mt], bfr[nt],
                                                              acc[mt][nt], 0, 0, 0);
  }

  // epilogue: C/D layout col=lane&15, row=quad*4+reg  [m89-verified]
#pragma unroll
  for (int mt = 0; mt < 4; ++mt) {
    long rbase = m0 + wm * 64 + mt * 16 + quad * 4;
#pragma unroll
    for (int nt = 0; nt < 4; ++nt) {
      int colg = n0 + wn * 64 + nt * 16 + lrow;
      float badd = bias ? bias[colg] : 0.0f;
      f32x4 v = acc[mt][nt];
#pragma unroll
      for (int r = 0; r < 4; ++r) {
        if constexpr (CF32)
          ((float*)Cp)[(rbase + r) * (long)ldc + colg] = v[r] + badd;
        else
          ((u16*)Cp)[(rbase + r) * (long)ldc + colg] = f2bf(v[r] + badd);
      }
    }
  }
}

// ---------------------------------------------------------------------------
// Attention: one block (256 thr) per b.
// qkv[b*16+f][0:512)=Q, [512:1024)=K, [1024:1536)=V, bf16.  O overwrites Q.
// LDS row stride padded 1536->1544 u16 (3088B) to break bank aliasing.
// ---------------------------------------------------------------------------
#define RS 1544

__global__ __launch_bounds__(256) void attn_k(
    u16* __restrict__ qkv, const float* __restrict__ table /*[32][8] fp32*/)
{
  __shared__ __align__(16) u16 sQ[16 * RS];     // 49408 B
  __shared__ float S[8 * 16 * 16];              // 8 KB, scores then probs
  const int tid = threadIdx.x;
  const long base = (long)blockIdx.x * (16 * 1536);

  {
    const uint4* src = (const uint4*)(qkv + base);   // 3072 x 16B
    uint4* dst = (uint4*)sQ;
#pragma unroll
    for (int r = 0; r < 12; ++r) {
      int idx = r * 256 + tid;
      int row = idx / 192;               // 192 uint4 per logical row
      int c   = idx - row * 192;
      dst[row * 193 + c] = src[idx];     // padded stride: 193 uint4 = 1544 u16
    }
  }
  __syncthreads();

  // ---- scores: thread -> (h = tid>>5, j = slot&15, i in {ibase..ibase+7}) ----
  {
    const int h = tid >> 5;
    const int slot = tid & 31;
    const int j = slot & 15;
    const int ibase = (slot >> 4) * 8;
    float kr[64];
    const u16* kp = sQ + j * RS + 512 + h * 64;
#pragma unroll
    for (int d = 0; d < 64; d += 2) {
      uint32_t u = *(const uint32_t*)(kp + d);
      kr[d] = bf2f((u16)u); kr[d + 1] = bf2f((u16)(u >> 16));
    }
#pragma unroll
    for (int r = 0; r < 8; ++r) {
      int i = ibase + r;
      const u16* qp = sQ + i * RS + h * 64;   // broadcast across 16 lanes
      float acc = 0.f;
#pragma unroll
      for (int d = 0; d < 64; d += 2) {
        uint32_t u = *(const uint32_t*)(qp + d);
        acc = fmaf(bf2f((u16)u), kr[d], acc);
        acc = fmaf(bf2f((u16)(u >> 16)), kr[d + 1], acc);
      }
      // T5 bucket, exact for F=16: n=i-j; |n|<8 -> |n|; 8-11 -> 8; 12-15 -> 9; +16 if n<0
      int n = i - j;
      int an = n < 0 ? -n : n;
      int bb = an < 8 ? an : (an < 12 ? 8 : 9);
      int bucket = (n < 0 ? 16 : 0) + bb;
      S[(h * 16 + i) * 16 + j] = acc * 0.125f + table[bucket * 8 + h];
    }
  }
  __syncthreads();

  // ---- softmax over j: one thread per (h,i) row ----
  if (tid < 128) {
    float* row = S + tid * 16;
    float m = row[0];
#pragma unroll
    for (int j = 1; j < 16; ++j) m = fmaxf(m, row[j]);
    float e[16]; float s = 0.f;
#pragma unroll
    for (int j = 0; j < 16; ++j) { e[j] = __expf(row[j] - m); s += e[j]; }
    float inv = 1.0f / s;
#pragma unroll
    for (int j = 0; j < 16; ++j) row[j] = e[j] * inv;
  }
  __syncthreads();

  // ---- PV: out[f][c] = sum_j P[h][f][j] * V[j][c];  write over Q cols ----
#pragma unroll 4
  for (int r = 0; r < 32; ++r) {
    int e = r * 256 + tid;         // [0, 8192)
    int f = e >> 9;
    int c = e & 511;
    int h = c >> 6;
    const float* p = S + (h * 16 + f) * 16;   // broadcast within 64-col head
    float acc = 0.f;
#pragma unroll
    for (int jj = 0; jj < 16; ++jj)
      acc = fmaf(p[jj], bf2f(sQ[jj * RS + 1024 + c]), acc);
    qkv[base + f * 1536 + c] = f2bf(acc);     // coalesced 2B stores
  }
}

// ---------------------------------------------------------------------------
extern "C" void kernel_launch(void* const* d_in, const int* in_sizes, int n_in,
                              void* d_out, int out_size, void* d_ws, size_t ws_size,
                              hipStream_t stream) {
  (void)in_sizes; (void)n_in; (void)out_size; (void)ws_size;
  const float* hs = (const float*)d_in[0];
  const float* Wq = (const float*)d_in[1];
  const float* Wk = (const float*)d_in[2];
  const float* Wv = (const float*)d_in[3];
  const float* Wo = (const float*)d_in[4];
  const float* bo = (const float*)d_in[5];
  const float* tb = (const float*)d_in[6];
  float* out = (float*)d_out;

  u16* WT  = (u16*)d_ws;                       // 2048*512 bf16 = 2 MB
  u16* qkv = (u16*)((char*)d_ws + (4ull << 20));  // @ +4MB: [131072][1536] bf16 = 403 MB
  u16* Abf = (u16*)d_out;                      // scratch: 134 MB bf16 in 268 MB out buf
                                               // (out not written until final GEMM)

  convert_bf16<<<32768, 256, 0, stream>>>(hs, Abf);   // 131072*512/8/256
  pack_weights<<<4096, 256, 0, stream>>>(Wq, Wk, Wv, Wo, WT);

  dim3 g1(12, 1024);                            // (N/128, M/128): N-tile fastest
  gemm_core<false, false><<<g1, 256, 0, stream>>>(Abf, 512, WT, nullptr, qkv, 1536);

  attn_k<<<8192, 256, 0, stream>>>(qkv, tb);

  dim3 g3(4, 1024);                             // (N/128, M/128)
  gemm_core<false, true><<<g3, 256, 0, stream>>>(qkv, 1536, WT + 1536 * 512, bo, out, 512);
}

// Round 2
// 1006.909 us; speedup vs baseline: 1.2475x; 1.0485x over previous
//
#include <hip/hip_runtime.h>
#include <stdint.h>

typedef unsigned short u16;
typedef __attribute__((ext_vector_type(8))) __bf16 bf16x8;
typedef __attribute__((ext_vector_type(4))) float f32x4;

#define GLOBAL_AS __attribute__((address_space(1)))
#define LDS_AS __attribute__((address_space(3)))

__device__ __forceinline__ float bf2f(u16 v) {
  union { uint32_t u; float f; } x; x.u = (uint32_t)v << 16; return x.f;
}
__device__ __forceinline__ u16 f2bf(float f) {
  union { float f; uint32_t u; } x; x.f = f;
  uint32_t u = x.u + 0x7fffu + ((x.u >> 16) & 1u);
  return (u16)(u >> 16);
}

// ---------------------------------------------------------------------------
// Kernel 0: pack fp32 weights -> bf16, transposed.
// WT[2048][512]: rows [0,512)=Wq^T, [512,1024)=Wk^T, [1024,1536)=Wv^T,
//                rows [1536,2048)=Wo^T.  WT[n][k] = W(k,n) as bf16 (RNE).
// ---------------------------------------------------------------------------
__global__ void pack_weights(const float* __restrict__ Wq, const float* __restrict__ Wk,
                             const float* __restrict__ Wv, const float* __restrict__ Wo,
                             u16* __restrict__ WT) {
  int g = blockIdx.x * 256 + threadIdx.x;      // [0, 2048*512)
  int n = g >> 9;
  int k = g & 511;
  const float* src = (n < 1024) ? ((n < 512) ? Wq : Wk) : ((n < 1536) ? Wv : Wo);
  WT[g] = f2bf(src[k * 512 + (n & 511)]);
}

// ---------------------------------------------------------------------------
// Kernel 0b: hidden_states fp32 -> bf16 (RNE), streaming, 8 elems/thread.
// Output goes into scratch (d_out reused; not needed until final GEMM).
// ---------------------------------------------------------------------------
__global__ __launch_bounds__(256) void convert_bf16(const float* __restrict__ src,
                                                    u16* __restrict__ dst) {
  long i = ((long)blockIdx.x * 256 + threadIdx.x) * 8;
  float4 a = *(const float4*)(src + i);
  float4 b = *(const float4*)(src + i + 4);
  uint4 w;
  w.x = (uint32_t)f2bf(a.x) | ((uint32_t)f2bf(a.y) << 16);
  w.y = (uint32_t)f2bf(a.z) | ((uint32_t)f2bf(a.w) << 16);
  w.z = (uint32_t)f2bf(b.x) | ((uint32_t)f2bf(b.y) << 16);
  w.w = (uint32_t)f2bf(b.z) | ((uint32_t)f2bf(b.w) << 16);
  *(uint4*)(dst + i) = w;
}

// ---------------------------------------------------------------------------
// GEMM core: C[M,N] = A[M,K=512] * BT[N,K=512]^T (+ bias), fp32 accumulate.
// 128x128 tile, BK=32, 256 threads = 2x2 waves, each wave 4x4 MFMA 16x16x32.
// Logical block id is XCD-swizzled (T1): nwg%8==0 for both call sites, so
// the 8-way round-robin HW dispatch gives each XCD a contiguous logical
// chunk -> the gridDim.x N-tiles sharing an A-tile hit the same L2.
// AF32: A is fp32 in global, converted to bf16 during LDS staging (ds_write).
//  else A is bf16, staged via global_load_lds width-16.
// CF32: C stored fp32 (+fp32 bias); else C stored bf16.
// ---------------------------------------------------------------------------
template <bool AF32, bool CF32>
__global__ __launch_bounds__(256, 2) void gemm_core(
    const void* __restrict__ Ap, int lda,
    const u16* __restrict__ BT,          // [N][512] bf16 row-major (pre-transposed)
    const float* __restrict__ bias,      // nullable, [N] fp32
    void* __restrict__ Cp, int ldc)
{
  __shared__ __align__(16) u16 lsA[128 * 32];   // [row m][k] 8KB
  __shared__ __align__(16) u16 lsB[128 * 32];   // [row n][k] 8KB

  const int tid  = threadIdx.x;
  const int wave = tid >> 6;
  const int lane = tid & 63;
  const int quad = lane >> 4;
  const int lrow = lane & 15;
  const int wm = wave & 1;
  const int wn = wave >> 1;

  // XCD-aware bijective swizzle (requires nwg % 8 == 0, else identity)
  const int gx = gridDim.x;
  int bid = blockIdx.y * gx + blockIdx.x;
  int nwg = gx * gridDim.y;
  int lb = (nwg & 7) ? bid : ((bid & 7) * (nwg >> 3) + (bid >> 3));
  const int  n0 = (lb % gx) * 128;
  const long m0 = (long)(lb / gx) * 128;

  // staging slots: slot = s*256 + tid; row = slot>>2, k-chunk = (slot&3)*8
  const int s0 = tid, s1 = 256 + tid;
  const u16* bgp0 = BT + (long)(n0 + (s0 >> 2)) * 512 + (s0 & 3) * 8;
  const u16* bgp1 = BT + (long)(n0 + (s1 >> 2)) * 512 + (s1 & 3) * 8;
  u16* lB0 = lsB + wave * 512;                 // wave-uniform LDS bases
  u16* lB1 = lsB + 2048 + wave * 512;

  // A staging pointers (either dtype); slot->LDS offset is slot*8 u16.
  const float* agf0 = (const float*)Ap + (m0 + (s0 >> 2)) * (long)lda + (s0 & 3) * 8;
  const float* agf1 = (const float*)Ap + (m0 + (s1 >> 2)) * (long)lda + (s1 & 3) * 8;
  const u16*   agb0 = (const u16*)Ap + (m0 + (s0 >> 2)) * (long)lda + (s0 & 3) * 8;
  const u16*   agb1 = (const u16*)Ap + (m0 + (s1 >> 2)) * (long)lda + (s1 & 3) * 8;
  u16* lA0 = lsA + wave * 512;
  u16* lA1 = lsA + 2048 + wave * 512;

  f32x4 acc[4][4] = {};

  for (int k0 = 0; k0 < 512; k0 += 32) {
    __syncthreads();   // previous iteration's ds_reads complete before overwrite
    if constexpr (AF32) {
      // load 2x8 fp32, convert RNE -> bf16, ds_write_b128 per slot
      float4 x0 = *(const float4*)(agf0 + k0);
      float4 x1 = *(const float4*)(agf0 + k0 + 4);
      float4 y0 = *(const float4*)(agf1 + k0);
      float4 y1 = *(const float4*)(agf1 + k0 + 4);
      uint4 w0, w1;
      w0.x = (uint32_t)f2bf(x0.x) | ((uint32_t)f2bf(x0.y) << 16);
      w0.y = (uint32_t)f2bf(x0.z) | ((uint32_t)f2bf(x0.w) << 16);
      w0.z = (uint32_t)f2bf(x1.x) | ((uint32_t)f2bf(x1.y) << 16);
      w0.w = (uint32_t)f2bf(x1.z) | ((uint32_t)f2bf(x1.w) << 16);
      w1.x = (uint32_t)f2bf(y0.x) | ((uint32_t)f2bf(y0.y) << 16);
      w1.y = (uint32_t)f2bf(y0.z) | ((uint32_t)f2bf(y0.w) << 16);
      w1.z = (uint32_t)f2bf(y1.x) | ((uint32_t)f2bf(y1.y) << 16);
      w1.w = (uint32_t)f2bf(y1.z) | ((uint32_t)f2bf(y1.w) << 16);
      *(uint4*)(lsA + s0 * 8) = w0;
      *(uint4*)(lsA + s1 * 8) = w1;
    } else {
      __builtin_amdgcn_global_load_lds((GLOBAL_AS const uint32_t*)(agb0 + k0),
                                       (LDS_AS uint32_t*)lA0, 16, 0, 0);
      __builtin_amdgcn_global_load_lds((GLOBAL_AS const uint32_t*)(agb1 + k0),
                                       (LDS_AS uint32_t*)lA1, 16, 0, 0);
    }
    __builtin_amdgcn_global_load_lds((GLOBAL_AS const uint32_t*)(bgp0 + k0),
                                     (LDS_AS uint32_t*)lB0, 16, 0, 0);
    __builtin_amdgcn_global_load_lds((GLOBAL_AS const uint32_t*)(bgp1 + k0),
                                     (LDS_AS uint32_t*)lB1, 16, 0, 0);
    __syncthreads();   // drains vmcnt+lgkmcnt: staging visible

    bf16x8 af[4], bfr[4];
#pragma unroll
    for (int t = 0; t < 4; ++t) {
      af[t]  = *(const bf16x8*)(lsA + (wm * 64 + t * 16 + lrow) * 32 + quad * 8);
      bfr[t] = *(const bf16x8*)(lsB + (wn * 64 + t * 16 + lrow) * 32 + quad * 8);
    }
#pragma unroll
    for (int mt = 0; mt < 4; ++mt)
#pragma unroll
      for (int nt = 0; nt < 4; ++nt)
        acc[mt][nt] = __builtin_amdgcn_mfma_f32_16x16x32_bf16(af[mt], bfr[nt],
                                                              acc[mt][nt], 0, 0, 0);
  }

  // epilogue: C/D layout col=lane&15, row=quad*4+reg  [m89-verified]
#pragma unroll
  for (int mt = 0; mt < 4; ++mt) {
    long rbase = m0 + wm * 64 + mt * 16 + quad * 4;
#pragma unroll
    for (int nt = 0; nt < 4; ++nt) {
      int colg = n0 + wn * 64 + nt * 16 + lrow;
      float badd = bias ? bias[colg] : 0.0f;
      f32x4 v = acc[mt][nt];
#pragma unroll
      for (int r = 0; r < 4; ++r) {
        if constexpr (CF32)
          ((float*)Cp)[(rbase + r) * (long)ldc + colg] = v[r] + badd;
        else
          ((u16*)Cp)[(rbase + r) * (long)ldc + colg] = f2bf(v[r] + badd);
      }
    }
  }
}

// ---------------------------------------------------------------------------
// Attention: one block (256 thr) per b.
// qkv[b*16+f][0:512)=Q, [512:1024)=K, [1024:1536)=V, bf16.  O overwrites Q.
// LDS row stride padded 1536->1544 u16 (3088B) to break bank aliasing.
// v2: all LDS traffic b128-vectorized (was scalar u16/u32 -> LDS-issue-bound).
// fma accumulation order preserved exactly vs v1 -> bit-identical output.
// ---------------------------------------------------------------------------
#define RS 1544

__global__ __launch_bounds__(256) void attn_k(
    u16* __restrict__ qkv, const float* __restrict__ table /*[32][8] fp32*/)
{
  __shared__ __align__(16) u16 sQ[16 * RS];     // 49408 B
  __shared__ float S[8 * 16 * 16];              // 8 KB, scores then probs
  const int tid = threadIdx.x;
  const long base = (long)blockIdx.x * (16 * 1536);

  {
    const uint4* src = (const uint4*)(qkv + base);   // 3072 x 16B
    uint4* dst = (uint4*)sQ;
#pragma unroll
    for (int r = 0; r < 12; ++r) {
      int idx = r * 256 + tid;
      int row = idx / 192;               // 192 uint4 per logical row
      int c   = idx - row * 192;
      dst[row * 193 + c] = src[idx];     // padded stride: 193 uint4 = 1544 u16
    }
  }
  __syncthreads();

  // ---- scores: thread -> (h = tid>>5, j = slot&15, i in {ibase..ibase+7}) ----
  {
    const int h = tid >> 5;
    const int slot = tid & 31;
    const int j = slot & 15;
    const int ibase = (slot >> 4) * 8;
    float kr[64];
    const uint4* kp = (const uint4*)(sQ + j * RS + 512 + h * 64);   // 16B aligned
#pragma unroll
    for (int t = 0; t < 8; ++t) {
      uint4 u = kp[t];
      kr[t * 8 + 0] = bf2f((u16)u.x); kr[t * 8 + 1] = bf2f((u16)(u.x >> 16));
      kr[t * 8 + 2] = bf2f((u16)u.y); kr[t * 8 + 3] = bf2f((u16)(u.y >> 16));
      kr[t * 8 + 4] = bf2f((u16)u.z); kr[t * 8 + 5] = bf2f((u16)(u.z >> 16));
      kr[t * 8 + 6] = bf2f((u16)u.w); kr[t * 8 + 7] = bf2f((u16)(u.w >> 16));
    }
#pragma unroll
    for (int r = 0; r < 8; ++r) {
      int i = ibase + r;
      const uint4* qp = (const uint4*)(sQ + i * RS + h * 64);
      float acc = 0.f;
#pragma unroll
      for (int t = 0; t < 8; ++t) {
        uint4 u = qp[t];
        acc = fmaf(bf2f((u16)u.x),         kr[t * 8 + 0], acc);
        acc = fmaf(bf2f((u16)(u.x >> 16)), kr[t * 8 + 1], acc);
        acc = fmaf(bf2f((u16)u.y),         kr[t * 8 + 2], acc);
        acc = fmaf(bf2f((u16)(u.y >> 16)), kr[t * 8 + 3], acc);
        acc = fmaf(bf2f((u16)u.z),         kr[t * 8 + 4], acc);
        acc = fmaf(bf2f((u16)(u.z >> 16)), kr[t * 8 + 5], acc);
        acc = fmaf(bf2f((u16)u.w),         kr[t * 8 + 6], acc);
        acc = fmaf(bf2f((u16)(u.w >> 16)), kr[t * 8 + 7], acc);
      }
      // T5 bucket, exact for F=16: n=i-j; |n|<8 -> |n|; 8-11 -> 8; 12-15 -> 9; +16 if n<0
      int n = i - j;
      int an = n < 0 ? -n : n;
      int bb = an < 8 ? an : (an < 12 ? 8 : 9);
      int bucket = (n < 0 ? 16 : 0) + bb;
      S[(h * 16 + i) * 16 + j] = acc * 0.125f + table[bucket * 8 + h];
    }
  }
  __syncthreads();

  // ---- softmax over j: one thread per (h,i) row ----
  if (tid < 128) {
    float* row = S + tid * 16;
    float m = row[0];
#pragma unroll
    for (int j = 1; j < 16; ++j) m = fmaxf(m, row[j]);
    float e[16]; float s = 0.f;
#pragma unroll
    for (int j = 0; j < 16; ++j) { e[j] = __expf(row[j] - m); s += e[j]; }
    float inv = 1.0f / s;
#pragma unroll
    for (int j = 0; j < 16; ++j) row[j] = e[j] * inv;
  }
  __syncthreads();

  // ---- PV: out[f][c8*8+e] = sum_j P[h][f][j] * V[j][c];  vectorized 8-wide ----
  // thread -> (c8 = tid&63 : 8-col chunk, f4 = tid>>6 : 4-frame group)
  {
    const int c8 = tid & 63;
    const int f4 = tid >> 6;
    const int h = c8 >> 3;
    uint4 vv[16];                        // all 16 V rows for this 8-col chunk
#pragma unroll
    for (int jj = 0; jj < 16; ++jj)
      vv[jj] = *(const uint4*)(sQ + jj * RS + 1024 + c8 * 8);
#pragma unroll
    for (int ff = 0; ff < 4; ++ff) {
      int f = f4 * 4 + ff;
      const f32x4* p = (const f32x4*)(S + (h * 16 + f) * 16);
      f32x4 p0 = p[0], p1 = p[1], p2 = p[2], p3 = p[3];
      float acc[8] = {};
#pragma unroll
      for (int jj = 0; jj < 16; ++jj) {
        float pj = (jj < 4) ? p0[jj & 3] : (jj < 8) ? p1[jj & 3]
                 : (jj < 12) ? p2[jj & 3] : p3[jj & 3];
        uint4 u = vv[jj];
        acc[0] = fmaf(pj, bf2f((u16)u.x),         acc[0]);
        acc[1] = fmaf(pj, bf2f((u16)(u.x >> 16)), acc[1]);
        acc[2] = fmaf(pj, bf2f((u16)u.y),         acc[2]);
        acc[3] = fmaf(pj, bf2f((u16)(u.y >> 16)), acc[3]);
        acc[4] = fmaf(pj, bf2f((u16)u.z),         acc[4]);
        acc[5] = fmaf(pj, bf2f((u16)(u.z >> 16)), acc[5]);
        acc[6] = fmaf(pj, bf2f((u16)u.w),         acc[6]);
        acc[7] = fmaf(pj, bf2f((u16)(u.w >> 16)), acc[7]);
      }
      uint4 w;
      w.x = (uint32_t)f2bf(acc[0]) | ((uint32_t)f2bf(acc[1]) << 16);
      w.y = (uint32_t)f2bf(acc[2]) | ((uint32_t)f2bf(acc[3]) << 16);
      w.z = (uint32_t)f2bf(acc[4]) | ((uint32_t)f2bf(acc[5]) << 16);
      w.w = (uint32_t)f2bf(acc[6]) | ((uint32_t)f2bf(acc[7]) << 16);
      *(uint4*)(qkv + base + f * 1536 + c8 * 8) = w;   // coalesced 16B stores
    }
  }
}

// ---------------------------------------------------------------------------
extern "C" void kernel_launch(void* const* d_in, const int* in_sizes, int n_in,
                              void* d_out, int out_size, void* d_ws, size_t ws_size,
                              hipStream_t stream) {
  (void)in_sizes; (void)n_in; (void)out_size; (void)ws_size;
  const float* hs = (const float*)d_in[0];
  const float* Wq = (const float*)d_in[1];
  const float* Wk = (const float*)d_in[2];
  const float* Wv = (const float*)d_in[3];
  const float* Wo = (const float*)d_in[4];
  const float* bo = (const float*)d_in[5];
  const float* tb = (const float*)d_in[6];
  float* out = (float*)d_out;

  u16* WT  = (u16*)d_ws;                       // 2048*512 bf16 = 2 MB
  u16* qkv = (u16*)((char*)d_ws + (4ull << 20));  // @ +4MB: [131072][1536] bf16 = 403 MB
  u16* Abf = (u16*)d_out;                      // scratch: 134 MB bf16 in 268 MB out buf
                                               // (out not written until final GEMM)

  convert_bf16<<<32768, 256, 0, stream>>>(hs, Abf);   // 131072*512/8/256
  pack_weights<<<4096, 256, 0, stream>>>(Wq, Wk, Wv, Wo, WT);

  dim3 g1(12, 1024);                            // (N/128, M/128): N-tile fastest
  gemm_core<false, false><<<g1, 256, 0, stream>>>(Abf, 512, WT, nullptr, qkv, 1536);

  attn_k<<<8192, 256, 0, stream>>>(qkv, tb);

  dim3 g3(4, 1024);                             // (N/128, M/128)
  gemm_core<false, true><<<g3, 256, 0, stream>>>(qkv, 1536, WT + 1536 * 512, bo, out, 512);
}